// Round 5
// baseline (227.212 us; speedup 1.0000x reference)
//
#include <hip/hip_runtime.h>
#include <math.h>

#define C_CAND 10

// 12-byte vector loads; rows are 12B-strided so only 4B-aligned.
typedef float vf3 __attribute__((ext_vector_type(3), aligned(4)));
typedef int   vi3 __attribute__((ext_vector_type(3), aligned(4)));
typedef int   v2i __attribute__((ext_vector_type(2)));  // 8B, naturally aligned

// Bit-identical point-triangle "merged distance". Op order mirrors numpy
// exactly; contract(off) forbids FMA fusion (IEEE div/sqrt match numpy).
__device__ __forceinline__ float tri_merged(
    float qx, float qy, float qz,
    float v0x, float v0y, float v0z,
    float v1x, float v1y, float v1z,
    float v2x, float v2y, float v2z)
{
#pragma clang fp contract(off)
    const float e10x = v1x - v0x, e10y = v1y - v0y, e10z = v1z - v0z;
    const float e21x = v2x - v1x, e21y = v2y - v1y, e21z = v2z - v1z;
    const float e02x = v0x - v2x, e02y = v0y - v2y, e02z = v0z - v2z;

    // fN = -cross(e10, e02)
    const float crx = e10y*e02z - e10z*e02y;
    const float cry = e10z*e02x - e10x*e02z;
    const float crz = e10x*e02y - e10y*e02x;
    const float fNx = -crx, fNy = -cry, fNz = -crz;

    const float a0x = qx - v0x, a0y = qy - v0y, a0z = qz - v0z;
    const float a1x = qx - v1x, a1y = qy - v1y, a1z = qz - v1z;
    const float a2x = qx - v2x, a2y = qy - v2y, a2z = qz - v2z;

    const float num_ab = (a0x*e10x + a0y*e10y) + a0z*e10z;
    const float den_ab = fmaxf((e10x*e10x + e10y*e10y) + e10z*e10z, 1e-9f);
    const float uab = num_ab / den_ab;

    const float num_bc = (a1x*e21x + a1y*e21y) + a1z*e21z;
    const float den_bc = fmaxf((e21x*e21x + e21y*e21y) + e21z*e21z, 1e-9f);
    const float ubc = num_bc / den_bc;

    const float num_ca = (a2x*e02x + a2y*e02y) + a2z*e02z;
    const float den_ca = fmaxf((e02x*e02x + e02y*e02y) + e02z*e02z, 1e-9f);
    const float uca = num_ca / den_ca;

    const bool t1 = (uca > 1.0f) && (uab < 0.0f);
    const bool t2 = (uab > 1.0f) && (ubc < 0.0f);
    const bool t3 = (ubc > 1.0f) && (uca < 0.0f);

    // _is_not_above: dot(cross(fN, e), p - v) <= 0
    const float c0x = fNy*e10z - fNz*e10y;
    const float c0y = fNz*e10x - fNx*e10z;
    const float c0z = fNx*e10y - fNy*e10x;
    const bool na0 = ((c0x*a0x + c0y*a0y) + c0z*a0z) <= 0.0f;

    const float c1x = fNy*e21z - fNz*e21y;
    const float c1y = fNz*e21x - fNx*e21z;
    const float c1z = fNx*e21y - fNy*e21x;
    const bool na1 = ((c1x*a1x + c1y*a1y) + c1z*a1z) <= 0.0f;

    const float c2x = fNy*e02z - fNz*e02y;
    const float c2y = fNz*e02x - fNx*e02z;
    const float c2z = fNx*e02y - fNy*e02x;
    const bool na2 = ((c2x*a2x + c2y*a2y) + c2z*a2z) <= 0.0f;

    const bool t4 = (uab >= 0.0f) && (uab <= 1.0f) && na0;
    const bool t5 = (ubc >= 0.0f) && (ubc <= 1.0f) && na1 && !t4;
    const bool t6 = (uca >= 0.0f) && (uca <= 1.0f) && na2 && !t4 && !t5;
    const bool t0 = !(t1 || t2 || t3 || t4 || t5 || t6);

    const float nrm = sqrtf((fNx*fNx + fNy*fNy) + fNz*fNz);
    const float dnm = fmaxf(nrm, 1e-9f);
    const float unx = fNx / dnm;
    const float uny = fNy / dnm;
    const float unz = fNz / dnm;

    const float d0 = (a0x*unx + a0y*uny) + a0z*unz;
    const float d1 = sqrtf((a0x*a0x + a0y*a0y) + a0z*a0z);
    const float d2 = sqrtf((a1x*a1x + a1y*a1y) + a1z*a1z);
    const float d3 = sqrtf((a2x*a2x + a2y*a2y) + a2z*a2z);

    const float p4x = v0x + e10x*uab, p4y = v0y + e10y*uab, p4z = v0z + e10z*uab;
    const float p5x = v1x + e21x*ubc, p5y = v1y + e21y*ubc, p5z = v1z + e21z*ubc;
    const float p6x = v2x + e02x*uca, p6y = v2y + e02y*uca, p6z = v2z + e02z*uca;

    const float g4x = qx - p4x, g4y = qy - p4y, g4z = qz - p4z;
    const float g5x = qx - p5x, g5y = qy - p5y, g5z = qz - p5z;
    const float g6x = qx - p6x, g6y = qy - p6y, g6z = qz - p6z;

    const float d4 = sqrtf((g4x*g4x + g4y*g4y) + g4z*g4z);
    const float d5 = sqrtf((g5x*g5x + g5y*g5y) + g5z*g5z);
    const float d6 = sqrtf((g6x*g6x + g6y*g6y) + g6z*g6z);

    float merged = d0 * (t0 ? 1.0f : 0.0f);
    merged = merged + d1 * (t1 ? 1.0f : 0.0f);
    merged = merged + d2 * (t2 ? 1.0f : 0.0f);
    merged = merged + d3 * (t3 ? 1.0f : 0.0f);
    merged = merged + d4 * (t4 ? 1.0f : 0.0f);
    merged = merged + d5 * (t5 ? 1.0f : 0.0f);
    merged = merged + d6 * (t6 ? 1.0f : 0.0f);
    return merged;
}

// Plain __launch_bounds__(256): no min-waves clamp (R3's clamp caused ~1KB/
// thread scratch spill). Arrays below are only indexed with unroll-constant
// indices -> SROA to registers (R2-proven safe even at depth-1 prefetch).
__global__ __launch_bounds__(256) void wootGlobalToLocal_kernel(
    const float* __restrict__ query_xyz,
    const float* __restrict__ temp_verts,
    const int*   __restrict__ faces,
    const int*   __restrict__ cand_ids,
    float*       __restrict__ out_ret,
    float*       __restrict__ out_md,
    int n)
{
    int i = blockIdx.x * blockDim.x + threadIdx.x;
    if (i >= n) return;

    // Streaming traffic nontemporal (R2: cut table-thrash fetch 140->30MB).
    const vf3 q = __builtin_nontemporal_load((const vf3*)(query_xyz + 3*i));
    const float qx = q.x, qy = q.y, qz = q.z;

    // All 10 cand ids upfront: five nt dwordx2, unpacked to named scalars.
    const v2i* cp = (const v2i*)(cand_ids + i * C_CAND);
    const v2i c01 = __builtin_nontemporal_load(cp + 0);
    const v2i c23 = __builtin_nontemporal_load(cp + 1);
    const v2i c45 = __builtin_nontemporal_load(cp + 2);
    const v2i c67 = __builtin_nontemporal_load(cp + 3);
    const v2i c89 = __builtin_nontemporal_load(cp + 4);
    const int cid[C_CAND] = { c01.x, c01.y, c23.x, c23.y, c45.x,
                              c45.y, c67.x, c67.y, c89.x, c89.y };

    // Software pipeline: face row prefetched 2 ahead, vertex rows 1 ahead.
    // R4 showed VGPR=36 / VALUBusy=39%: the cand->face->vert dependent chain
    // was fully exposed each iteration. Here tri_merged (~150 VALU) covers
    // the next candidate's gather latency.
    vi3 f_cur = *(const vi3*)(faces + 3*cid[0]);
    vi3 f_nxt = *(const vi3*)(faces + 3*cid[1]);
    vf3 v0c = *(const vf3*)(temp_verts + 3*f_cur.x);
    vf3 v1c = *(const vf3*)(temp_verts + 3*f_cur.y);
    vf3 v2c = *(const vf3*)(temp_verts + 3*f_cur.z);

    float best_abs = 0.0f;
    float best_md  = 0.0f;
    int   best_f   = 0;

#pragma unroll
    for (int j = 0; j < C_CAND; ++j) {
        // Issue next-next face row and next vertex rows BEFORE the compute;
        // their first use is next iteration, so waitcnt lands after compute.
        vi3 f_nn;
        if (j + 2 < C_CAND)
            f_nn = *(const vi3*)(faces + 3*cid[j + 2]);
        vf3 v0n, v1n, v2n;
        if (j + 1 < C_CAND) {
            v0n = *(const vf3*)(temp_verts + 3*f_nxt.x);
            v1n = *(const vf3*)(temp_verts + 3*f_nxt.y);
            v2n = *(const vf3*)(temp_verts + 3*f_nxt.z);
        }

        const float merged = tri_merged(qx, qy, qz,
                                        v0c.x, v0c.y, v0c.z,
                                        v1c.x, v1c.y, v1c.z,
                                        v2c.x, v2c.y, v2c.z);
        const float am = fabsf(merged);
        // strict < keeps FIRST minimum — matches np.argmin tie-break
        if (j == 0 || am < best_abs) {
            best_abs = am;
            best_md  = merged;
            best_f   = cid[j];
        }

        // Rotate pipeline registers (SSA renames under full unroll — free).
        if (j + 1 < C_CAND) {
            f_cur = f_nxt;
            v0c = v0n; v1c = v1n; v2c = v2n;
        }
        if (j + 2 < C_CAND)
            f_nxt = f_nn;
    }

    __builtin_nontemporal_store((float)best_f, &out_ret[i]);
    __builtin_nontemporal_store(best_md,       &out_md[i]);
}

extern "C" void kernel_launch(void* const* d_in, const int* in_sizes, int n_in,
                              void* d_out, int out_size, void* d_ws, size_t ws_size,
                              hipStream_t stream) {
    const float* query_xyz  = (const float*)d_in[0];
    const float* temp_verts = (const float*)d_in[1];
    const int*   faces      = (const int*)d_in[2];
    const int*   cand_ids   = (const int*)d_in[3];

    const int n = in_sizes[0] / 3;   // N queries

    float* out_ret = (float*)d_out;  // first N: chosen face id (as float)
    float* out_md  = out_ret + n;    // next N: merged distance

    const int block = 256;
    const int grid  = (n + block - 1) / block;
    wootGlobalToLocal_kernel<<<grid, block, 0, stream>>>(
        query_xyz, temp_verts, faces, cand_ids, out_ret, out_md, n);
}

// Round 7
// 174.912 us; speedup vs baseline: 1.2990x; 1.2990x over previous
//
#include <hip/hip_runtime.h>
#include <math.h>

#define C_CAND 10

// 12-byte vector loads; rows are 12B-strided so only 4B-aligned.
typedef float vf3 __attribute__((ext_vector_type(3), aligned(4)));
typedef int   vi3 __attribute__((ext_vector_type(3), aligned(4)));
typedef float v4f __attribute__((ext_vector_type(4)));  // 16B, aligned

// Bit-identical point-triangle "merged distance". Op order mirrors numpy
// exactly; contract(off) forbids FMA fusion (IEEE div/sqrt match numpy).
__device__ __forceinline__ float tri_merged(
    float qx, float qy, float qz,
    float v0x, float v0y, float v0z,
    float v1x, float v1y, float v1z,
    float v2x, float v2y, float v2z)
{
#pragma clang fp contract(off)
    const float e10x = v1x - v0x, e10y = v1y - v0y, e10z = v1z - v0z;
    const float e21x = v2x - v1x, e21y = v2y - v1y, e21z = v2z - v1z;
    const float e02x = v0x - v2x, e02y = v0y - v2y, e02z = v0z - v2z;

    // fN = -cross(e10, e02)
    const float crx = e10y*e02z - e10z*e02y;
    const float cry = e10z*e02x - e10x*e02z;
    const float crz = e10x*e02y - e10y*e02x;
    const float fNx = -crx, fNy = -cry, fNz = -crz;

    const float a0x = qx - v0x, a0y = qy - v0y, a0z = qz - v0z;
    const float a1x = qx - v1x, a1y = qy - v1y, a1z = qz - v1z;
    const float a2x = qx - v2x, a2y = qy - v2y, a2z = qz - v2z;

    const float num_ab = (a0x*e10x + a0y*e10y) + a0z*e10z;
    const float den_ab = fmaxf((e10x*e10x + e10y*e10y) + e10z*e10z, 1e-9f);
    const float uab = num_ab / den_ab;

    const float num_bc = (a1x*e21x + a1y*e21y) + a1z*e21z;
    const float den_bc = fmaxf((e21x*e21x + e21y*e21y) + e21z*e21z, 1e-9f);
    const float ubc = num_bc / den_bc;

    const float num_ca = (a2x*e02x + a2y*e02y) + a2z*e02z;
    const float den_ca = fmaxf((e02x*e02x + e02y*e02y) + e02z*e02z, 1e-9f);
    const float uca = num_ca / den_ca;

    const bool t1 = (uca > 1.0f) && (uab < 0.0f);
    const bool t2 = (uab > 1.0f) && (ubc < 0.0f);
    const bool t3 = (ubc > 1.0f) && (uca < 0.0f);

    // _is_not_above: dot(cross(fN, e), p - v) <= 0
    const float c0x = fNy*e10z - fNz*e10y;
    const float c0y = fNz*e10x - fNx*e10z;
    const float c0z = fNx*e10y - fNy*e10x;
    const bool na0 = ((c0x*a0x + c0y*a0y) + c0z*a0z) <= 0.0f;

    const float c1x = fNy*e21z - fNz*e21y;
    const float c1y = fNz*e21x - fNx*e21z;
    const float c1z = fNx*e21y - fNy*e21x;
    const bool na1 = ((c1x*a1x + c1y*a1y) + c1z*a1z) <= 0.0f;

    const float c2x = fNy*e02z - fNz*e02y;
    const float c2y = fNz*e02x - fNx*e02z;
    const float c2z = fNx*e02y - fNy*e02x;
    const bool na2 = ((c2x*a2x + c2y*a2y) + c2z*a2z) <= 0.0f;

    const bool t4 = (uab >= 0.0f) && (uab <= 1.0f) && na0;
    const bool t5 = (ubc >= 0.0f) && (ubc <= 1.0f) && na1 && !t4;
    const bool t6 = (uca >= 0.0f) && (uca <= 1.0f) && na2 && !t4 && !t5;
    const bool t0 = !(t1 || t2 || t3 || t4 || t5 || t6);

    const float nrm = sqrtf((fNx*fNx + fNy*fNy) + fNz*fNz);
    const float dnm = fmaxf(nrm, 1e-9f);
    const float unx = fNx / dnm;
    const float uny = fNy / dnm;
    const float unz = fNz / dnm;

    const float d0 = (a0x*unx + a0y*uny) + a0z*unz;
    const float d1 = sqrtf((a0x*a0x + a0y*a0y) + a0z*a0z);
    const float d2 = sqrtf((a1x*a1x + a1y*a1y) + a1z*a1z);
    const float d3 = sqrtf((a2x*a2x + a2y*a2y) + a2z*a2z);

    const float p4x = v0x + e10x*uab, p4y = v0y + e10y*uab, p4z = v0z + e10z*uab;
    const float p5x = v1x + e21x*ubc, p5y = v1y + e21y*ubc, p5z = v1z + e21z*ubc;
    const float p6x = v2x + e02x*uca, p6y = v2y + e02y*uca, p6z = v2z + e02z*uca;

    const float g4x = qx - p4x, g4y = qy - p4y, g4z = qz - p4z;
    const float g5x = qx - p5x, g5y = qy - p5y, g5z = qz - p5z;
    const float g6x = qx - p6x, g6y = qy - p6y, g6z = qz - p6z;

    const float d4 = sqrtf((g4x*g4x + g4y*g4y) + g4z*g4z);
    const float d5 = sqrtf((g5x*g5x + g5y*g5y) + g5z*g5z);
    const float d6 = sqrtf((g6x*g6x + g6y*g6y) + g6z*g6z);

    float merged = d0 * (t0 ? 1.0f : 0.0f);
    merged = merged + d1 * (t1 ? 1.0f : 0.0f);
    merged = merged + d2 * (t2 ? 1.0f : 0.0f);
    merged = merged + d3 * (t3 ? 1.0f : 0.0f);
    merged = merged + d4 * (t4 ? 1.0f : 0.0f);
    merged = merged + d5 * (t5 ? 1.0f : 0.0f);
    merged = merged + d6 * (t6 ? 1.0f : 0.0f);
    return merged;
}

// -------- Pass 1: pack each face's 9 vertex floats into a 64B-stride record.
// Face reads are COALESCED (thread t reads faces[3t..3t+2]); only 3 divergent
// vert gathers per face = 600k gathers total (vs 15M in the main loop).
__global__ __launch_bounds__(256) void pack_faces_kernel(
    const float* __restrict__ temp_verts,
    const int*   __restrict__ faces,
    float*       __restrict__ packed,   // 16 floats (64B) per face
    int F)
{
    int t = blockIdx.x * blockDim.x + threadIdx.x;
    if (t >= F) return;

    const vi3 fi = *(const vi3*)(faces + 3*t);
    const vf3 v0 = *(const vf3*)(temp_verts + 3*fi.x);
    const vf3 v1 = *(const vf3*)(temp_verts + 3*fi.y);
    const vf3 v2 = *(const vf3*)(temp_verts + 3*fi.z);

    v4f* dst = (v4f*)(packed + (size_t)16 * t);
    v4f a; a.x = v0.x; a.y = v0.y; a.z = v0.z; a.w = v1.x;
    v4f b; b.x = v1.y; b.y = v1.z; b.z = v2.x; b.w = v2.y;
    v4f c; c.x = v2.z; c.y = 0.0f; c.z = 0.0f; c.w = 0.0f;
    dst[0] = a; dst[1] = b; dst[2] = c;   // last 16B of record unused
}

// -------- Pass 2: one-hop gather. Per candidate: 3 INDEPENDENT dwordx4 from
// one 64B-aligned record = exactly ONE L1 line touched (R1/R4 touched ~4-5
// scattered lines through a 3-deep dependent chain). Plain rolled loop +
// unroll 2: R2/R5 proved manual pipelining -> VGPR ~174 -> 11% occupancy.
__global__ __launch_bounds__(256) void woot_main_kernel(
    const float* __restrict__ query_xyz,
    const float* __restrict__ packed,
    const int*   __restrict__ cand_ids,
    float*       __restrict__ out_ret,
    float*       __restrict__ out_md,
    int n)
{
    int i = blockIdx.x * blockDim.x + threadIdx.x;
    if (i >= n) return;

    // Streaming traffic nontemporal: don't evict the packed table from L2.
    const vf3 q = __builtin_nontemporal_load((const vf3*)(query_xyz + 3*i));
    const float qx = q.x, qy = q.y, qz = q.z;

    float best_abs = 0.0f;
    float best_md  = 0.0f;
    int   best_f   = 0;

#pragma unroll 2
    for (int j = 0; j < C_CAND; ++j) {
        const int f = __builtin_nontemporal_load(&cand_ids[i * C_CAND + j]);

        const v4f* rp = (const v4f*)(packed + (size_t)16 * f);
        const v4f r0 = rp[0];   // v0x v0y v0z v1x
        const v4f r1 = rp[1];   // v1y v1z v2x v2y
        const v4f r2 = rp[2];   // v2z  -   -   -

        const float merged = tri_merged(qx, qy, qz,
                                        r0.x, r0.y, r0.z,
                                        r0.w, r1.x, r1.y,
                                        r1.z, r1.w, r2.x);
        const float am = fabsf(merged);
        // strict < keeps FIRST minimum — matches np.argmin tie-break
        if (j == 0 || am < best_abs) {
            best_abs = am;
            best_md  = merged;
            best_f   = f;
        }
    }

    __builtin_nontemporal_store((float)best_f, &out_ret[i]);
    __builtin_nontemporal_store(best_md,       &out_md[i]);
}

// -------- Fallback (ws too small): R4's direct kernel, proven 133 us.
__global__ __launch_bounds__(256) void woot_direct_kernel(
    const float* __restrict__ query_xyz,
    const float* __restrict__ temp_verts,
    const int*   __restrict__ faces,
    const int*   __restrict__ cand_ids,
    float*       __restrict__ out_ret,
    float*       __restrict__ out_md,
    int n)
{
    int i = blockIdx.x * blockDim.x + threadIdx.x;
    if (i >= n) return;

    const vf3 q = __builtin_nontemporal_load((const vf3*)(query_xyz + 3*i));
    const float qx = q.x, qy = q.y, qz = q.z;

    float best_abs = 0.0f;
    float best_md  = 0.0f;
    int   best_f   = 0;

    for (int j = 0; j < C_CAND; ++j) {
        const int f = __builtin_nontemporal_load(&cand_ids[i * C_CAND + j]);
        const vi3 fi = *(const vi3*)(faces + 3*f);
        const vf3 v0 = *(const vf3*)(temp_verts + 3*fi.x);
        const vf3 v1 = *(const vf3*)(temp_verts + 3*fi.y);
        const vf3 v2 = *(const vf3*)(temp_verts + 3*fi.z);

        const float merged = tri_merged(qx, qy, qz,
                                        v0.x, v0.y, v0.z,
                                        v1.x, v1.y, v1.z,
                                        v2.x, v2.y, v2.z);
        const float am = fabsf(merged);
        if (j == 0 || am < best_abs) {
            best_abs = am;
            best_md  = merged;
            best_f   = f;
        }
    }

    __builtin_nontemporal_store((float)best_f, &out_ret[i]);
    __builtin_nontemporal_store(best_md,       &out_md[i]);
}

extern "C" void kernel_launch(void* const* d_in, const int* in_sizes, int n_in,
                              void* d_out, int out_size, void* d_ws, size_t ws_size,
                              hipStream_t stream) {
    const float* query_xyz  = (const float*)d_in[0];
    const float* temp_verts = (const float*)d_in[1];
    const int*   faces      = (const int*)d_in[2];
    const int*   cand_ids   = (const int*)d_in[3];

    const int n = in_sizes[0] / 3;   // N queries
    const int F = in_sizes[2] / 3;   // number of faces

    float* out_ret = (float*)d_out;  // first N: chosen face id (as float)
    float* out_md  = out_ret + n;    // next N: merged distance

    const int block = 256;
    const int grid_n = (n + block - 1) / block;

    const size_t need = (size_t)F * 16 * sizeof(float);  // 12.8 MB at F=200k
    if (ws_size >= need) {
        float* packed = (float*)d_ws;
        const int grid_f = (F + block - 1) / block;
        pack_faces_kernel<<<grid_f, block, 0, stream>>>(
            temp_verts, faces, packed, F);
        woot_main_kernel<<<grid_n, block, 0, stream>>>(
            query_xyz, packed, cand_ids, out_ret, out_md, n);
    } else {
        woot_direct_kernel<<<grid_n, block, 0, stream>>>(
            query_xyz, temp_verts, faces, cand_ids, out_ret, out_md, n);
    }
}